// Round 1
// 395.479 us; speedup vs baseline: 1.0049x; 1.0049x over previous
//
#include <hip/hip_runtime.h>
#include <math.h>

// B=4, S=4096 -> 16384 tokens; H=4096; E=64; TOP_K=2
#define TOKENS 16384
#define HDIM 4096
#define NE 64

#define BM 64                 // tokens per block
#define BK 32                 // k per LDS chunk (per K-group)
#define NKG 2                 // intra-block K groups (512 threads total)
#define KSLICE (HDIM / NKG)   // 2048 per group
#define LDSP 68               // padded LDS row stride in floats (16B-aligned b128 reads)
#define TILE (BK * LDSP)      // floats per staging tile (2176)

// Fused router: GEMM (logits) + softmax + top-2 in one kernel. No workspace.
// 256 blocks x 512 threads. Each block: 64 tokens. Two 256-thread K-groups
// each cover H/2 with the proven 4x4-microtile register-prefetch loop;
// partials meet in an LDS logits tile (reusing group-0 staging LDS), then
// 8 waves run shuffle softmax + ballot top-2 (lowest-index tie-break).
__global__ __launch_bounds__(512, 2) void router_fused(const float* __restrict__ A,
                                                       const float* __restrict__ W,
                                                       float* __restrict__ out) {
  // [group0: As | Ws][group1: As | Ws]; group0's pair (4352 floats = 17408 B)
  // is reused after the K-loop as the 64 x LDSP logits tile (4352 floats).
  __shared__ float smem[NKG * 2 * TILE];

  const int tid = threadIdx.x;
  const int kg = tid >> 8;   // K group 0/1
  const int t = tid & 255;   // id within group
  const int bt = blockIdx.x; // token tile (64 tokens)

  // staging map: row = t>>2 (0..63), two float4 slots at cols (t&3)*4 and +16
  const int sr = t >> 2;
  const int sc = (t & 3) * 4;

  const float* Ab = A + (size_t)(bt * BM + sr) * HDIM + (size_t)kg * KSLICE + sc;
  const float* Wb = W + (size_t)sr * HDIM + (size_t)kg * KSLICE + sc;  // sr<64 == E

  float* As = smem + kg * (2 * TILE);  // [k][token_row]
  float* Ws = As + TILE;               // [k][expert_row]

  // compute map: tx = expert group (16), ty = token group (4 tokens each)
  const int tx = t & 15;
  const int ty = t >> 4;

  float acc[4][4];
#pragma unroll
  for (int i = 0; i < 4; ++i)
#pragma unroll
    for (int j = 0; j < 4; ++j) acc[i][j] = 0.f;

  // register-buffered prefetch: load chunk 0
  float4 a0 = *(const float4*)(Ab);
  float4 a1 = *(const float4*)(Ab + 16);
  float4 w0 = *(const float4*)(Wb);
  float4 w1 = *(const float4*)(Wb + 16);

  for (int kc = 0; kc < KSLICE; kc += BK) {
    // stage current chunk from registers (2 lanes/bank -> free)
    As[(sc + 0) * LDSP + sr] = a0.x;
    As[(sc + 1) * LDSP + sr] = a0.y;
    As[(sc + 2) * LDSP + sr] = a0.z;
    As[(sc + 3) * LDSP + sr] = a0.w;
    As[(sc + 16) * LDSP + sr] = a1.x;
    As[(sc + 17) * LDSP + sr] = a1.y;
    As[(sc + 18) * LDSP + sr] = a1.z;
    As[(sc + 19) * LDSP + sr] = a1.w;
    Ws[(sc + 0) * LDSP + sr] = w0.x;
    Ws[(sc + 1) * LDSP + sr] = w0.y;
    Ws[(sc + 2) * LDSP + sr] = w0.z;
    Ws[(sc + 3) * LDSP + sr] = w0.w;
    Ws[(sc + 16) * LDSP + sr] = w1.x;
    Ws[(sc + 17) * LDSP + sr] = w1.y;
    Ws[(sc + 18) * LDSP + sr] = w1.z;
    Ws[(sc + 19) * LDSP + sr] = w1.w;
    __syncthreads();

    // prefetch next chunk into registers (overlaps with compute below)
    if (kc + BK < KSLICE) {
      a0 = *(const float4*)(Ab + kc + BK);
      a1 = *(const float4*)(Ab + kc + BK + 16);
      w0 = *(const float4*)(Wb + kc + BK);
      w1 = *(const float4*)(Wb + kc + BK + 16);
    }

#pragma unroll
    for (int k = 0; k < BK; ++k) {
      float4 av = *(const float4*)&As[k * LDSP + ty * 4];  // broadcast across tx
      float4 wv = *(const float4*)&Ws[k * LDSP + tx * 4];  // 2 addrs/bank: free
      const float a[4] = {av.x, av.y, av.z, av.w};
      const float w[4] = {wv.x, wv.y, wv.z, wv.w};
#pragma unroll
      for (int i = 0; i < 4; ++i)
#pragma unroll
        for (int j = 0; j < 4; ++j) acc[i][j] = fmaf(a[i], w[j], acc[i][j]);
    }
    __syncthreads();
  }

  // reduce the two K-group partials into the logits tile (aliases group-0 LDS;
  // safe: everyone is past the last compute barrier)
  float* L = smem;  // [BM][LDSP]
  if (kg == 0) {
#pragma unroll
    for (int i = 0; i < 4; ++i)
      *(float4*)&L[(ty * 4 + i) * LDSP + tx * 4] =
          make_float4(acc[i][0], acc[i][1], acc[i][2], acc[i][3]);
  }
  __syncthreads();
  if (kg == 1) {
#pragma unroll
    for (int i = 0; i < 4; ++i) {
      float4* p = (float4*)&L[(ty * 4 + i) * LDSP + tx * 4];
      float4 v = *p;
      *p = make_float4(v.x + acc[i][0], v.y + acc[i][1], v.z + acc[i][2],
                       v.w + acc[i][3]);
    }
  }
  __syncthreads();

  // softmax + top-2: 8 waves x 8 tokens, lane = expert
  const int lane = tid & 63;
  const int wv8 = tid >> 6;
#pragma unroll
  for (int r = 0; r < 8; ++r) {
    const int lt = wv8 * 8 + r;
    const int tok = bt * BM + lt;
    const float l = L[lt * LDSP + lane];  // 2-way bank alias: free

    float m = l;
#pragma unroll
    for (int off = 32; off >= 1; off >>= 1) m = fmaxf(m, __shfl_xor(m, off, 64));

    const float e = expf(l - m);
    float sum = e;
#pragma unroll
    for (int off = 32; off >= 1; off >>= 1) sum += __shfl_xor(sum, off, 64);

    const float p = e / sum;
    out[(size_t)tok * NE + lane] = p;

    float m0 = p;
#pragma unroll
    for (int off = 32; off >= 1; off >>= 1) m0 = fmaxf(m0, __shfl_xor(m0, off, 64));
    const unsigned long long b0 = __ballot(p == m0);
    const int i0 = __ffsll(b0) - 1;

    const float pm = (lane == i0) ? -1.f : p;
    float m1 = pm;
#pragma unroll
    for (int off = 32; off >= 1; off >>= 1) m1 = fmaxf(m1, __shfl_xor(m1, off, 64));
    const unsigned long long b1 = __ballot(pm == m1);
    const int i1 = __ffsll(b1) - 1;

    if (lane == 0) {
      float* idxo = out + (size_t)TOKENS * NE + (size_t)tok * 2;
      idxo[0] = (float)i0;
      idxo[1] = (float)i1;
      float* wo = out + (size_t)TOKENS * NE + (size_t)TOKENS * 2 + (size_t)tok * 2;
      const float d = m0 + m1;
      wo[0] = m0 / d;
      wo[1] = m1 / d;
    }
  }
}

extern "C" void kernel_launch(void* const* d_in, const int* in_sizes, int n_in,
                              void* d_out, int out_size, void* d_ws, size_t ws_size,
                              hipStream_t stream) {
  const float* A = (const float*)d_in[0];  // hidden_states [16384, 4096] f32
  const float* W = (const float*)d_in[1];  // gate_weight   [64, 4096] f32
  float* out = (float*)d_out;
  (void)d_ws;                              // no workspace: partials round-trip fused away

  router_fused<<<dim3(TOKENS / BM), 512, 0, stream>>>(A, W, out);
}